// Round 8
// baseline (241.669 us; speedup 1.0000x reference)
//
#include <hip/hip_runtime.h>
#include <hip/hip_bf16.h>

#define NSEQ 4096
#define FT 256
#define BK 64
#define NT (NSEQ / BK)  // 64

typedef __attribute__((ext_vector_type(8))) short bf16x8;
typedef __attribute__((ext_vector_type(4))) float f32x4;

__device__ __forceinline__ ushort f2bf(float f) {
  __hip_bfloat16 h = __float2bfloat16(f);
  return *reinterpret_cast<const ushort*>(&h);
}

// XOR swizzle of 16B granules within a 128B row (kernel A only).
__device__ __forceinline__ int swz(int row, int byteInRow) {
  return row * 128 + (byteInRow ^ ((row & 7) << 4));
}

__device__ __forceinline__ void mma_step(const char* lAp, const char* lBp,
                                         int lane, int wm, int wn,
                                         f32x4 acc[2][4]) {
  const int r16 = lane & 15;
  const int g16 = (lane >> 4) * 16;
#pragma unroll
  for (int kk = 0; kk < 2; ++kk) {
    const int kb = kk * 64 + g16;
    bf16x8 a[2], b[4];
#pragma unroll
    for (int mi = 0; mi < 2; ++mi) {
      const int row = wm * 32 + mi * 16 + r16;
      a[mi] = *reinterpret_cast<const bf16x8*>(lAp + swz(row, kb));
    }
#pragma unroll
    for (int ni = 0; ni < 4; ++ni) {
      const int row = wn * 64 + ni * 16 + r16;
      b[ni] = *reinterpret_cast<const bf16x8*>(lBp + swz(row, kb));
    }
#pragma unroll
    for (int mi = 0; mi < 2; ++mi)
#pragma unroll
      for (int ni = 0; ni < 4; ++ni)
        acc[mi][ni] = __builtin_amdgcn_mfma_f32_16x16x32_bf16(a[mi], b[ni],
                                                             acc[mi][ni], 0, 0, 0);
  }
}

// ---------------- Kernel A: hT[b][o][n] = (seq @ W^T + b) as bf16 ----------------
__global__ __launch_bounds__(512) void linear_kernel(
    const float* __restrict__ seq, const float* __restrict__ W,
    const float* __restrict__ bias, ushort* __restrict__ hT) {
  __shared__ __align__(16) ushort lA[2][64 * 64];
  __shared__ __align__(16) ushort lB[2][256 * 64];

  const int tid = threadIdx.x;
  const int lane = tid & 63;
  const int wid = tid >> 6;
  const int wm = wid >> 2, wn = wid & 3;
  const int m0 = blockIdx.x * 64;

  const int ar = tid >> 4, ac = tid & 15;

  f32x4 rA[2];
  f32x4 rB[8];

  auto gload = [&](int t) {
    const int k0 = t * BK;
#pragma unroll
    for (int p = 0; p < 2; ++p)
      rA[p] = *reinterpret_cast<const f32x4*>(
          seq + (size_t)(m0 + ar + p * 32) * FT + k0 + ac * 4);
#pragma unroll
    for (int p = 0; p < 8; ++p)
      rB[p] = *reinterpret_cast<const f32x4*>(
          W + (size_t)(ar + p * 32) * FT + k0 + ac * 4);
  };
  auto lwrite = [&](int buf) {
    char* lAp = (char*)lA[buf];
    char* lBp = (char*)lB[buf];
#pragma unroll
    for (int p = 0; p < 2; ++p) {
      ushort4 u = make_ushort4(f2bf(rA[p][0]), f2bf(rA[p][1]), f2bf(rA[p][2]), f2bf(rA[p][3]));
      *reinterpret_cast<ushort4*>(lAp + swz(ar + p * 32, ac * 8)) = u;
    }
#pragma unroll
    for (int p = 0; p < 8; ++p) {
      ushort4 u = make_ushort4(f2bf(rB[p][0]), f2bf(rB[p][1]), f2bf(rB[p][2]), f2bf(rB[p][3]));
      *reinterpret_cast<ushort4*>(lBp + swz(ar + p * 32, ac * 8)) = u;
    }
  };

  f32x4 acc[2][4];
  const f32x4 zero = {0.f, 0.f, 0.f, 0.f};
#pragma unroll
  for (int mi = 0; mi < 2; ++mi)
#pragma unroll
    for (int ni = 0; ni < 4; ++ni) acc[mi][ni] = zero;

  gload(0);
  lwrite(0);
  const int NTA = FT / BK;  // 4
  for (int t = 0; t < NTA; ++t) {
    const int cur = t & 1;
    __syncthreads();
    if (t + 1 < NTA) gload(t + 1);
    mma_step((const char*)lA[cur], (const char*)lB[cur], lane, wm, wn, acc);
    if (t + 1 < NTA) lwrite(cur ^ 1);
  }

#pragma unroll
  for (int mi = 0; mi < 2; ++mi) {
    const int grow = m0 + wm * 32 + mi * 16 + ((lane >> 4) << 2);
    const int batch = grow >> 12;
    const int n = grow & (NSEQ - 1);
#pragma unroll
    for (int ni = 0; ni < 4; ++ni) {
      const int o = wn * 64 + ni * 16 + (lane & 15);
      const float bo = bias[o];
      ushort4 u;
      u.x = f2bf(acc[mi][ni][0] + bo);
      u.y = f2bf(acc[mi][ni][1] + bo);
      u.z = f2bf(acc[mi][ni][2] + bo);
      u.w = f2bf(acc[mi][ni][3] + bo);
      *reinterpret_cast<ushort4*>(hT + (size_t)(batch * FT + o) * NSEQ + n) = u;
    }
  }
}

// ---------------- Kernel B: out = PReLU(adj @ h), barrier-minimal ----------------
// 256-thr blocks (4 waves, col-split 4x64), 32-row tiles, grid 512 = 2
// blocks/CU. Both operands direct-to-register as native MFMA fragments
// (A: 8 f32x4/wave + in-reg cvt; B: 8 bf16x8/wave). 2-deep register sets,
// sched_barrier(0) walls pin the prefetch (R6's failure was unpinned loads
// sinking into uses). One light __syncthreads per 2 K-steps keeps the 4
// waves aligned for L1 A-reuse. LDS only for the epilogue.
__global__ __launch_bounds__(256, 2) void bmm_prelu_kernel(
    const float* __restrict__ adj, const ushort* __restrict__ hT,
    const float* __restrict__ alphaP, float* __restrict__ out) {
  __shared__ __align__(16) float lo[32 * 264];  // epilogue only (33.8 KB)

  const int tid = threadIdx.x;
  const int lane = tid & 63;
  const int wid = tid >> 6;  // 0..3 = wave's 64-col group

  // XCD-contiguous remap (bijective: 512 = 8 * 64).
  const int bid = blockIdx.x;
  const int sbid = (bid & 7) * 64 + (bid >> 3);
  const int batch = sbid >> 7;        // 128 row-tiles per batch
  const int m0 = (sbid & 127) * 32;

  const int r16 = lane & 15, g8 = (lane >> 4) * 8;
  const float* aBase = adj + ((size_t)batch * NSEQ + m0 + r16) * NSEQ + g8;
  const ushort* bBase = hT + ((size_t)batch * FT + wid * 64 + r16) * NSEQ + g8;

  typedef f32x4 ASet[2][2][2];  // [mi][kk][p]
  typedef bf16x8 BSet[4][2];    // [ni][kk]
  ASet A0, A1;
  BSet B0, B1;

  f32x4 acc[2][4];
  const f32x4 zero = {0.f, 0.f, 0.f, 0.f};
#pragma unroll
  for (int mi = 0; mi < 2; ++mi)
#pragma unroll
    for (int ni = 0; ni < 4; ++ni) acc[mi][ni] = zero;

  auto load_set = [&](int t, ASet& A, BSet& B) {
    const int k0 = t * BK;
#pragma unroll
    for (int mi = 0; mi < 2; ++mi)
#pragma unroll
      for (int kk = 0; kk < 2; ++kk)
#pragma unroll
        for (int p = 0; p < 2; ++p)
          A[mi][kk][p] = *reinterpret_cast<const f32x4*>(
              aBase + (size_t)mi * 16 * NSEQ + k0 + kk * 32 + p * 4);
#pragma unroll
    for (int ni = 0; ni < 4; ++ni)
#pragma unroll
      for (int kk = 0; kk < 2; ++kk)
        B[ni][kk] = *reinterpret_cast<const bf16x8*>(
            bBase + (size_t)ni * 16 * NSEQ + k0 + kk * 32);
  };

  auto compute = [&](ASet& A, BSet& B) {
#pragma unroll
    for (int kk = 0; kk < 2; ++kk) {
      bf16x8 a[2];
#pragma unroll
      for (int mi = 0; mi < 2; ++mi)
#pragma unroll
        for (int p = 0; p < 2; ++p)
#pragma unroll
          for (int e = 0; e < 4; ++e)
            a[mi][p * 4 + e] = (short)f2bf(A[mi][kk][p][e]);
#pragma unroll
      for (int mi = 0; mi < 2; ++mi)
#pragma unroll
        for (int ni = 0; ni < 4; ++ni)
          acc[mi][ni] = __builtin_amdgcn_mfma_f32_16x16x32_bf16(
              a[mi], B[ni][kk], acc[mi][ni], 0, 0, 0);
    }
  };

  // 2-deep pinned pipeline over 64 K-steps.
  load_set(0, A0, B0);
  load_set(1, A1, B1);
  for (int j = 0; j < 31; ++j) {
    __builtin_amdgcn_sched_barrier(0);
    compute(A0, B0);
    __builtin_amdgcn_sched_barrier(0);
    load_set(2 * j + 2, A0, B0);
    __builtin_amdgcn_sched_barrier(0);
    compute(A1, B1);
    __builtin_amdgcn_sched_barrier(0);
    load_set(2 * j + 3, A1, B1);
    __syncthreads();  // realign the 4 waves for L1 A-reuse (cheap, 4 waves)
  }
  __builtin_amdgcn_sched_barrier(0);
  compute(A0, B0);  // t = 62
  compute(A1, B1);  // t = 63

  // Epilogue: PReLU -> LDS (padded pitch) -> coalesced nontemporal rows.
  const float alpha = *alphaP;
  const int PITCH = 264;
#pragma unroll
  for (int mi = 0; mi < 2; ++mi) {
    const int rbase = mi * 16 + ((lane >> 4) << 2);
#pragma unroll
    for (int ni = 0; ni < 4; ++ni) {
      const int o = wid * 64 + ni * 16 + (lane & 15);
#pragma unroll
      for (int j = 0; j < 4; ++j) {
        float v = acc[mi][ni][j];
        v = v > 0.f ? v : alpha * v;
        lo[(rbase + j) * PITCH + o] = v;
      }
    }
  }
  __syncthreads();
  float* outB = out + ((size_t)batch * NSEQ + m0) * FT;
  const int r = tid >> 3, c8 = tid & 7;
#pragma unroll
  for (int k = 0; k < 8; ++k) {
    const int g = c8 + k * 8;
    f32x4 v = *reinterpret_cast<const f32x4*>(lo + r * PITCH + g * 4);
    __builtin_nontemporal_store(v, reinterpret_cast<f32x4*>(outB + (size_t)r * FT + g * 4));
  }
}

extern "C" void kernel_launch(void* const* d_in, const int* in_sizes, int n_in,
                              void* d_out, int out_size, void* d_ws, size_t ws_size,
                              hipStream_t stream) {
  const float* seq = (const float*)d_in[0];
  const float* adj = (const float*)d_in[1];
  const float* W = (const float*)d_in[2];
  const float* bias = (const float*)d_in[3];
  const float* alpha = (const float*)d_in[4];
  float* out = (float*)d_out;
  ushort* hT = (ushort*)d_ws;  // [4][256][4096] bf16 = 8 MB

  linear_kernel<<<256, 512, 0, stream>>>(seq, W, bias, hT);
  bmm_prelu_kernel<<<512, 256, 0, stream>>>(adj, hT, alpha, out);
}

// Round 9
// 83.628 us; speedup vs baseline: 2.8898x; 2.8898x over previous
//
#include <hip/hip_runtime.h>
#include <hip/hip_bf16.h>

#define NSEQ 4096
#define FT 256
#define BK 64
#define BKB 128
#define NTB (NSEQ / BKB)  // 32

typedef __attribute__((ext_vector_type(8))) short bf16x8;
typedef __attribute__((ext_vector_type(4))) float f32x4;

__device__ __forceinline__ ushort f2bf(float f) {
  __hip_bfloat16 h = __float2bfloat16(f);
  return *reinterpret_cast<const ushort*>(&h);
}

// XOR swizzle of 16B granules within a 128B row (kernel A staging).
__device__ __forceinline__ int swz(int row, int byteInRow) {
  return row * 128 + (byteInRow ^ ((row & 7) << 4));
}

__device__ __forceinline__ void mma_step(const char* lAp, const char* lBp,
                                         int lane, int wm, int wn,
                                         f32x4 acc[2][4]) {
  const int r16 = lane & 15;
  const int g16 = (lane >> 4) * 16;
#pragma unroll
  for (int kk = 0; kk < 2; ++kk) {
    const int kb = kk * 64 + g16;
    bf16x8 a[2], b[4];
#pragma unroll
    for (int mi = 0; mi < 2; ++mi) {
      const int row = wm * 32 + mi * 16 + r16;
      a[mi] = *reinterpret_cast<const bf16x8*>(lAp + swz(row, kb));
    }
#pragma unroll
    for (int ni = 0; ni < 4; ++ni) {
      const int row = wn * 64 + ni * 16 + r16;
      b[ni] = *reinterpret_cast<const bf16x8*>(lBp + swz(row, kb));
    }
#pragma unroll
    for (int mi = 0; mi < 2; ++mi)
#pragma unroll
      for (int ni = 0; ni < 4; ++ni)
        acc[mi][ni] = __builtin_amdgcn_mfma_f32_16x16x32_bf16(a[mi], b[ni],
                                                             acc[mi][ni], 0, 0, 0);
  }
}

// ---------------- Kernel A: hT[b][o][n] = (seq @ W^T + b) as bf16 ----------------
__global__ __launch_bounds__(512) void linear_kernel(
    const float* __restrict__ seq, const float* __restrict__ W,
    const float* __restrict__ bias, ushort* __restrict__ hT) {
  __shared__ __align__(16) ushort lA[2][64 * 64];
  __shared__ __align__(16) ushort lB[2][256 * 64];

  const int tid = threadIdx.x;
  const int lane = tid & 63;
  const int wid = tid >> 6;
  const int wm = wid >> 2, wn = wid & 3;
  const int m0 = blockIdx.x * 64;

  const int ar = tid >> 4, ac = tid & 15;

  f32x4 rA[2];
  f32x4 rB[8];

  auto gload = [&](int t) {
    const int k0 = t * BK;
#pragma unroll
    for (int p = 0; p < 2; ++p)
      rA[p] = *reinterpret_cast<const f32x4*>(
          seq + (size_t)(m0 + ar + p * 32) * FT + k0 + ac * 4);
#pragma unroll
    for (int p = 0; p < 8; ++p)
      rB[p] = *reinterpret_cast<const f32x4*>(
          W + (size_t)(ar + p * 32) * FT + k0 + ac * 4);
  };
  auto lwrite = [&](int buf) {
    char* lAp = (char*)lA[buf];
    char* lBp = (char*)lB[buf];
#pragma unroll
    for (int p = 0; p < 2; ++p) {
      ushort4 u = make_ushort4(f2bf(rA[p][0]), f2bf(rA[p][1]), f2bf(rA[p][2]), f2bf(rA[p][3]));
      *reinterpret_cast<ushort4*>(lAp + swz(ar + p * 32, ac * 8)) = u;
    }
#pragma unroll
    for (int p = 0; p < 8; ++p) {
      ushort4 u = make_ushort4(f2bf(rB[p][0]), f2bf(rB[p][1]), f2bf(rB[p][2]), f2bf(rB[p][3]));
      *reinterpret_cast<ushort4*>(lBp + swz(ar + p * 32, ac * 8)) = u;
    }
  };

  f32x4 acc[2][4];
  const f32x4 zero = {0.f, 0.f, 0.f, 0.f};
#pragma unroll
  for (int mi = 0; mi < 2; ++mi)
#pragma unroll
    for (int ni = 0; ni < 4; ++ni) acc[mi][ni] = zero;

  gload(0);
  lwrite(0);
  const int NTA = FT / BK;  // 4
  for (int t = 0; t < NTA; ++t) {
    const int cur = t & 1;
    __syncthreads();
    if (t + 1 < NTA) gload(t + 1);
    mma_step((const char*)lA[cur], (const char*)lB[cur], lane, wm, wn, acc);
    if (t + 1 < NTA) lwrite(cur ^ 1);
  }

#pragma unroll
  for (int mi = 0; mi < 2; ++mi) {
    const int grow = m0 + wm * 32 + mi * 16 + ((lane >> 4) << 2);
    const int batch = grow >> 12;
    const int n = grow & (NSEQ - 1);
#pragma unroll
    for (int ni = 0; ni < 4; ++ni) {
      const int o = wn * 64 + ni * 16 + (lane & 15);
      const float bo = bias[o];
      ushort4 u;
      u.x = f2bf(acc[mi][ni][0] + bo);
      u.y = f2bf(acc[mi][ni][1] + bo);
      u.z = f2bf(acc[mi][ni][2] + bo);
      u.w = f2bf(acc[mi][ni][3] + bo);
      *reinterpret_cast<ushort4*>(hT + (size_t)(batch * FT + o) * NSEQ + n) = u;
    }
  }
}

// ---------------- Kernel B: out = PReLU(adj @ h), BK=128, 32 barriers ----------------
// BM=64, BN=256 (adj read once). 512 thr (8 waves 2x4), grid 256 (1 blk/CU).
// 2 lB bufs (64 KB) + 2 lA bufs (16 KB) = 160 KB LDS. Per iter: issue
// A(t+1)+B(t+1) at top, 32 MFMA/wave, counted vmcnt(8) for A-regs, vmcnt(0)
// only at the barrier (full-iter slack makes the drain ~free). Swizzle: each
// 256-B row = two independent 128-B half-rows with R7's proven XOR scheme:
// LDS[row][half][g] = global granule g ^ (row&7).
__global__ __launch_bounds__(512) void bmm_prelu_kernel(
    const float* __restrict__ adj, const ushort* __restrict__ hT,
    const float* __restrict__ alphaP, float* __restrict__ out) {
  __shared__ __align__(16) char smem[2 * 65536 + 2 * 16384];  // lB[2] | lA[2]

  const int tid = threadIdx.x;
  const int lane = tid & 63;
  const int wid = tid >> 6;
  const int wm = wid >> 2, wn = wid & 3;

  // XCD-contiguous remap (bijective: 256 = 8 * 32).
  const int bid = blockIdx.x;
  const int sbid = (bid & 7) * 32 + (bid >> 3);
  const int batch = sbid >> 6;
  const int m0 = (sbid & 63) * 64;

  const float* adjB = adj + (size_t)batch * NSEQ * NSEQ + (size_t)m0 * NSEQ;
  const ushort* hTB = hT + (size_t)batch * FT * NSEQ;

  auto lB = [&](int i) -> char* { return smem + i * 65536; };
  auto lA = [&](int i) -> char* { return smem + 131072 + i * 16384; };

  // adj staging geometry: thread -> row (0..63), 16-float chunk c (0..7).
  const int arow = tid >> 3, ac = tid & 7;
  // hT glds geometry: wave wid covers rows [wid*32, wid*32+32).
  const int bro = (lane >> 4);                 // row-in-quad
  const int bhalf = (lane >> 3) & 1;           // 128-B half
  f32x4 rS[4];

  f32x4 acc[2][4];
  const f32x4 zero = {0.f, 0.f, 0.f, 0.f};
#pragma unroll
  for (int mi = 0; mi < 2; ++mi)
#pragma unroll
    for (int ni = 0; ni < 4; ++ni) acc[mi][ni] = zero;

  auto issueA = [&](int t) {
    const int k0 = t * BKB;
#pragma unroll
    for (int q = 0; q < 4; ++q)
      rS[q] = *reinterpret_cast<const f32x4*>(
          adjB + (size_t)arow * NSEQ + k0 + ac * 16 + q * 4);
  };
  auto issueB = [&](int t, int ib) {
    const int k0 = t * BKB;
#pragma unroll
    for (int p = 0; p < 8; ++p) {
      const int grow = wid * 32 + p * 4 + bro;
      const int gsrc = (lane & 7) ^ (((p & 1) * 4 + bro) & 7);
      const ushort* gp = hTB + (size_t)grow * NSEQ + k0 + bhalf * 64 + gsrc * 8;
      char* lp = lB(ib) + wid * 8192 + p * 1024;  // wave-uniform; HW adds lane*16
      __builtin_amdgcn_global_load_lds(
          (const __attribute__((address_space(1))) void*)gp,
          (__attribute__((address_space(3))) void*)lp, 16, 0, 0);
    }
  };
  auto writeA = [&](int ia) {
    char* lAp = lA(ia);
    const int half = ac >> 2;
#pragma unroll
    for (int q = 0; q < 4; ++q) {
      ushort4 u = make_ushort4(f2bf(rS[q][0]), f2bf(rS[q][1]),
                               f2bf(rS[q][2]), f2bf(rS[q][3]));
      const int gih = (((ac & 3) * 2 + (q >> 1)) ^ (arow & 7));
      *reinterpret_cast<ushort4*>(lAp + arow * 256 + half * 128 + gih * 16 +
                                  (q & 1) * 8) = u;
    }
  };
  auto mma32 = [&](const char* lAp, const char* lBp) {
    const int r16 = lane & 15;
    const int sub = lane >> 4;
#pragma unroll
    for (int kk = 0; kk < 4; ++kk) {
      const int half = kk >> 1;
      const int gih = (((kk & 1) * 4 + sub) ^ (r16 & 7));
      const int bofs = half * 128 + gih * 16;
      bf16x8 a[2], b[4];
#pragma unroll
      for (int mi = 0; mi < 2; ++mi) {
        const int row = wm * 32 + mi * 16 + r16;
        a[mi] = *reinterpret_cast<const bf16x8*>(lAp + row * 256 + bofs);
      }
#pragma unroll
      for (int ni = 0; ni < 4; ++ni) {
        const int row = wn * 64 + ni * 16 + r16;
        b[ni] = *reinterpret_cast<const bf16x8*>(lBp + row * 256 + bofs);
      }
#pragma unroll
      for (int mi = 0; mi < 2; ++mi)
#pragma unroll
        for (int ni = 0; ni < 4; ++ni)
          acc[mi][ni] = __builtin_amdgcn_mfma_f32_16x16x32_bf16(
              a[mi], b[ni], acc[mi][ni], 0, 0, 0);
    }
  };

  // Prologue: stage tile 0.
  issueA(0);
  __builtin_amdgcn_sched_barrier(0);
  issueB(0, 0);
  __builtin_amdgcn_sched_barrier(0);
  asm volatile("s_waitcnt vmcnt(8)" ::: "memory");  // A0 regs ready
  __builtin_amdgcn_sched_barrier(0);
  writeA(0);
  asm volatile("s_waitcnt vmcnt(0) lgkmcnt(0)" ::: "memory");  // B0 + ds done
  __builtin_amdgcn_s_barrier();
  __builtin_amdgcn_sched_barrier(0);

  // body(t, cur=t&1): issue tile t+1 into bufs cur^1; compute tile t.
  auto body = [&](int t, int cur) {
    issueA(t + 1);
    __builtin_amdgcn_sched_barrier(0);
    issueB(t + 1, cur ^ 1);
    __builtin_amdgcn_sched_barrier(0);
    __builtin_amdgcn_s_setprio(1);
    mma32(lA(cur), lB(cur));
    __builtin_amdgcn_s_setprio(0);
    asm volatile("s_waitcnt vmcnt(8)" ::: "memory");  // A(t+1) regs ready
    __builtin_amdgcn_sched_barrier(0);
    writeA(cur ^ 1);
    asm volatile("s_waitcnt vmcnt(0) lgkmcnt(0)" ::: "memory");
    __builtin_amdgcn_s_barrier();
    __builtin_amdgcn_sched_barrier(0);
  };

  // 31 bodies (t = 0..30), then the final compute of tile 31.
  for (int j = 0; j < 15; ++j) {
    body(2 * j, 0);
    body(2 * j + 1, 1);
  }
  body(30, 0);
  __builtin_amdgcn_s_setprio(1);
  mma32(lA(1), lB(1));
  __builtin_amdgcn_s_setprio(0);

  // Epilogue: PReLU -> LDS overlay (padded pitch) -> coalesced rows.
  const float alpha = *alphaP;
  __syncthreads();
  float* lo = (float*)smem;  // 64 x 264 f32 = 66 KB
  const int PITCH = 264;
#pragma unroll
  for (int mi = 0; mi < 2; ++mi) {
    const int rbase = wm * 32 + mi * 16 + ((lane >> 4) << 2);
#pragma unroll
    for (int ni = 0; ni < 4; ++ni) {
      const int o = wn * 64 + ni * 16 + (lane & 15);
#pragma unroll
      for (int j = 0; j < 4; ++j) {
        float v = acc[mi][ni][j];
        v = v > 0.f ? v : alpha * v;
        lo[(rbase + j) * PITCH + o] = v;
      }
    }
  }
  __syncthreads();
  float* outB = out + ((size_t)batch * NSEQ + m0) * FT;
  const int r = tid >> 3, c8 = tid & 7;
#pragma unroll
  for (int k = 0; k < 8; ++k) {
    const int g = c8 + k * 8;
    f32x4 v = *reinterpret_cast<const f32x4*>(lo + r * PITCH + g * 4);
    __builtin_nontemporal_store(v, reinterpret_cast<f32x4*>(outB + (size_t)r * FT + g * 4));
  }
}

extern "C" void kernel_launch(void* const* d_in, const int* in_sizes, int n_in,
                              void* d_out, int out_size, void* d_ws, size_t ws_size,
                              hipStream_t stream) {
  const float* seq = (const float*)d_in[0];
  const float* adj = (const float*)d_in[1];
  const float* W = (const float*)d_in[2];
  const float* bias = (const float*)d_in[3];
  const float* alpha = (const float*)d_in[4];
  float* out = (float*)d_out;
  ushort* hT = (ushort*)d_ws;  // [4][256][4096] bf16 = 8 MB

  linear_kernel<<<256, 512, 0, stream>>>(seq, W, bias, hT);
  bmm_prelu_kernel<<<256, 512, 0, stream>>>(adj, hT, alpha, out);
}